// Round 4
// baseline (374.901 us; speedup 1.0000x reference)
//
#include <hip/hip_runtime.h>
#include <stdint.h>

#define N_UNITS   400
#define N_NEIGHB  64
#define C         3
#define S         2
#define T         10      // C + C*S + E, E=1
#define NSLICE    64      // spike slices for histogram kernels
#define HALF_NB   32      // neighborhoods per histogram half
#define HIST      (HALF_NB * N_UNITS)   // 12800 ints = 51.2 KB LDS

// ---------- JAX Threefry-2x32, key = (0, 1) (jax.random.key(1)) ----------
__device__ __forceinline__ uint32_t rotl32(uint32_t x, int d) {
    return (x << d) | (x >> (32 - d));
}

__device__ __forceinline__ void threefry_key01(uint32_t x0, uint32_t x1,
                                               uint32_t& o0, uint32_t& o1) {
    const uint32_t ks0 = 0u;
    const uint32_t ks1 = 1u;
    const uint32_t ks2 = 0x1BD11BDBu;  // 0x1BD11BDA ^ 0 ^ 1
    x0 += ks0; x1 += ks1;
#define TF_RND(r) { x0 += x1; x1 = rotl32(x1, r); x1 ^= x0; }
    TF_RND(13) TF_RND(15) TF_RND(26) TF_RND(6)
    x0 += ks1; x1 += ks2 + 1u;
    TF_RND(17) TF_RND(29) TF_RND(16) TF_RND(24)
    x0 += ks2; x1 += ks0 + 2u;
    TF_RND(13) TF_RND(15) TF_RND(26) TF_RND(6)
    x0 += ks0; x1 += ks1 + 3u;
    TF_RND(17) TF_RND(29) TF_RND(16) TF_RND(24)
    x0 += ks1; x1 += ks2 + 4u;
    TF_RND(13) TF_RND(15) TF_RND(26) TF_RND(6)
    x0 += ks2; x1 += ks0 + 5u;
#undef TF_RND
    o0 = x0; o1 = x1;
}

// jax_threefry_partitionable=True (default since jax 0.4.36):
// bits[i] = x0 ^ x1 of threefry2x32(key, (i >> 32, i & 0xffffffff)).
__device__ __forceinline__ int explore_index(int i, int ne) {
    uint32_t o0, o1;
    threefry_key01(0u, (uint32_t)i, o0, o1);
    uint32_t bits = o0 ^ o1;
    float u = __uint_as_float((bits >> 9) | 0x3F800000u) - 1.0f;
    int t = (int)floorf(u * (float)ne);
    return min(t, ne - 1);
}

// ---------- k1: phase-1 partial histograms (top0 x nb), LDS atomics only ----
__global__ void k_hist1(const int* __restrict__ top,
                        const int* __restrict__ nbid,
                        int* __restrict__ P, int n) {
    __shared__ int hist[HIST];
    for (int k = threadIdx.x; k < HIST; k += blockDim.x) hist[k] = 0;
    __syncthreads();
    int g = blockIdx.x, s = g >> 1, h = g & 1;
    int chunk = (n + NSLICE - 1) / NSLICE;
    int lo = s * chunk, hi = min(n, lo + chunk);
    for (int i = lo + threadIdx.x; i < hi; i += blockDim.x) {
        int nb = nbid[i];
        if ((nb >> 5) == h)
            atomicAdd(&hist[(nb & 31) * N_UNITS + top[i * 3]], 1);
    }
    __syncthreads();
    int* Pb = P + (size_t)g * HIST;
    for (int k = threadIdx.x; k < HIST; k += blockDim.x) Pb[k] = hist[k];
}

// ---------- k1b: reduce partials -> ws counts (nb-major) ----------
__global__ void k_reduce1(const int* __restrict__ P, int* __restrict__ wcounts) {
    int c = blockIdx.x * blockDim.x + threadIdx.x;
    if (c >= N_NEIGHB * N_UNITS) return;
    int nb = c / N_UNITS, u = c - nb * N_UNITS;
    int local = (nb & 31) * N_UNITS + u, h = nb >> 5;
    int sum = 0;
    for (int s = 0; s < NSLICE; ++s) sum += P[(size_t)(s * 2 + h) * HIST + local];
    wcounts[c] = sum;
}

// ---------- k1c: per-neighborhood sorted unit tables ----------
__global__ void k_tables(const int* __restrict__ wcounts,
                         int* __restrict__ wtbl, int* __restrict__ wne) {
    int b = threadIdx.x;
    if (b < N_NEIGHB) {
        int pos = 0;
        for (int u = 0; u < N_UNITS; ++u)
            if (wcounts[b * N_UNITS + u] > 0) wtbl[b * N_UNITS + pos++] = u;
        wne[b] = pos;
    }
}

// ---------- k3: full-candidate partial histograms (all 10 columns) --------
__global__ void k_hist2(const int* __restrict__ top,
                        const int* __restrict__ usn,
                        const int* __restrict__ nbid,
                        const int* __restrict__ wtbl,
                        const int* __restrict__ wne,
                        int* __restrict__ P, int n) {
    __shared__ int hist[HIST];
    __shared__ int s_usn[N_UNITS * S];
    __shared__ int s_ne[N_NEIGHB];
    for (int k = threadIdx.x; k < HIST; k += blockDim.x) hist[k] = 0;
    for (int k = threadIdx.x; k < N_UNITS * S; k += blockDim.x) s_usn[k] = usn[k];
    for (int k = threadIdx.x; k < N_NEIGHB; k += blockDim.x) s_ne[k] = wne[k];
    __syncthreads();
    int g = blockIdx.x, s = g >> 1, h = g & 1;
    int chunk = (n + NSLICE - 1) / NSLICE;
    int lo = s * chunk, hi = min(n, lo + chunk);
    for (int i = lo + threadIdx.x; i < hi; i += blockDim.x) {
        int nb = nbid[i];
        if ((nb >> 5) != h) continue;
        int* hrow = &hist[(nb & 31) * N_UNITS];
        int t0 = top[i * 3], t1 = top[i * 3 + 1], t2 = top[i * 3 + 2];
        atomicAdd(&hrow[t0], 1);
        atomicAdd(&hrow[t1], 1);
        atomicAdd(&hrow[t2], 1);
        atomicAdd(&hrow[s_usn[t0 * 2]], 1); atomicAdd(&hrow[s_usn[t0 * 2 + 1]], 1);
        atomicAdd(&hrow[s_usn[t1 * 2]], 1); atomicAdd(&hrow[s_usn[t1 * 2 + 1]], 1);
        atomicAdd(&hrow[s_usn[t2 * 2]], 1); atomicAdd(&hrow[s_usn[t2 * 2 + 1]], 1);
        int ne = s_ne[nb];
        if (ne > 0) {
            int t = explore_index(i, ne);
            atomicAdd(&hrow[wtbl[nb * N_UNITS + t]], 1);
        }
    }
    __syncthreads();
    int* Pb = P + (size_t)g * HIST;
    for (int k = threadIdx.x; k < HIST; k += blockDim.x) Pb[k] = hist[k];
}

// ---------- k3b: reduce partials -> final counts (u-major, float) ----------
__global__ void k_reduce2(const int* __restrict__ P, float* __restrict__ out_counts) {
    int c = blockIdx.x * blockDim.x + threadIdx.x;
    if (c >= N_NEIGHB * N_UNITS) return;
    int nb = c / N_UNITS, u = c - nb * N_UNITS;
    int local = (nb & 31) * N_UNITS + u, h = nb >> 5;
    int sum = 0;
    for (int s = 0; s < NSLICE; ++s) sum += P[(size_t)(s * 2 + h) * HIST + local];
    out_counts[u * N_NEIGHB + nb] = (float)sum;
}

// ---------- k2: per-spike candidates + scores ----------
__global__ void k_main(const float* __restrict__ logliks,
                       const int* __restrict__ top,
                       const int* __restrict__ usn,
                       const int* __restrict__ nbid,
                       const int* __restrict__ wtbl,
                       const int* __restrict__ wne,
                       float* __restrict__ out_cand,
                       float* __restrict__ out_scores,
                       int n) {
    __shared__ int   s_usn[N_UNITS * S];
    __shared__ float s_ll[N_UNITS];
    __shared__ int   s_ne[N_NEIGHB];
    for (int k = threadIdx.x; k < N_UNITS * S; k += blockDim.x) s_usn[k] = usn[k];
    for (int k = threadIdx.x; k < N_UNITS; k += blockDim.x)     s_ll[k]  = logliks[k];
    for (int k = threadIdx.x; k < N_NEIGHB; k += blockDim.x)    s_ne[k]  = wne[k];
    __syncthreads();

    int i = blockIdx.x * blockDim.x + threadIdx.x;
    if (i >= n) return;

    int nb = nbid[i];
    int cand[T];
    cand[0] = top[i * 3 + 0];
    cand[1] = top[i * 3 + 1];
    cand[2] = top[i * 3 + 2];
#pragma unroll
    for (int c = 0; c < C; ++c) {
        cand[C + 2 * c]     = s_usn[cand[c] * 2 + 0];
        cand[C + 2 * c + 1] = s_usn[cand[c] * 2 + 1];
    }
    int ne = s_ne[nb];
    if (ne > 0) {
        int t = explore_index(i, ne);
        cand[T - 1] = wtbl[nb * N_UNITS + t];
    } else {
        cand[T - 1] = -1;
    }

    float* oc = out_cand   + (size_t)i * T;
    float* os = out_scores + (size_t)i * T;
#pragma unroll
    for (int jj = 0; jj < T; ++jj) {
        bool dup = false;
#pragma unroll
        for (int k = 0; k < jj; ++k) dup |= (cand[k] == cand[jj]);
        int v = dup ? -1 : cand[jj];   // reference erases dups to -1
        oc[jj] = (float)v;
        os[jj] = (v >= 0) ? s_ll[v] : 0.0f;
    }
}

extern "C" void kernel_launch(void* const* d_in, const int* in_sizes, int n_in,
                              void* d_out, int out_size, void* d_ws, size_t ws_size,
                              hipStream_t stream) {
    const float* logliks = (const float*)d_in[0];
    const int*   top     = (const int*)d_in[1];
    const int*   usn     = (const int*)d_in[2];
    const int*   nbid    = (const int*)d_in[3];

    int n = in_sizes[3];          // N_SPIKES

    float* out        = (float*)d_out;
    float* out_cand   = out;
    float* out_counts = out + (size_t)n * T;
    float* out_scores = out_counts + (size_t)N_UNITS * N_NEIGHB;

    // Workspace: plain stores only (no global atomics anywhere).
    int* wcounts = (int*)d_ws;                         // 25600 (nb-major)
    int* wtbl    = wcounts + N_NEIGHB * N_UNITS;       // 25600
    int* wne     = wtbl + N_NEIGHB * N_UNITS;          // 64

    // Partial-histogram scratch lives in the scores region of d_out
    // (128 * 12800 ints = 6.55 MB << 40 MB); k_main overwrites it last.
    int* P = (int*)out_scores;

    const int bs = 256;
    k_hist1<<<2 * NSLICE, bs, 0, stream>>>(top, nbid, P, n);
    int m = N_NEIGHB * N_UNITS;
    k_reduce1<<<(m + bs - 1) / bs, bs, 0, stream>>>(P, wcounts);
    k_tables<<<1, 64, 0, stream>>>(wcounts, wtbl, wne);
    k_hist2<<<2 * NSLICE, bs, 0, stream>>>(top, usn, nbid, wtbl, wne, P, n);
    k_reduce2<<<(m + bs - 1) / bs, bs, 0, stream>>>(P, out_counts);
    k_main<<<(n + bs - 1) / bs, bs, 0, stream>>>(logliks, top, usn, nbid, wtbl, wne,
                                                 out_cand, out_scores, n);
}

// Round 5
// 260.349 us; speedup vs baseline: 1.4400x; 1.4400x over previous
//
#include <hip/hip_runtime.h>
#include <stdint.h>

#define N_UNITS   400
#define N_NEIGHB  64
#define C         3
#define S         2
#define T         10      // C + C*S + E, E=1
#define NSLICE    64      // spike slices for histogram kernels
#define HALF_NB   32      // neighborhoods per histogram half
#define HIST      (HALF_NB * N_UNITS)   // 12800 ints = 51.2 KB LDS

// ---------- JAX Threefry-2x32, key = (0, 1) (jax.random.key(1)) ----------
__device__ __forceinline__ uint32_t rotl32(uint32_t x, int d) {
    return (x << d) | (x >> (32 - d));
}

__device__ __forceinline__ void threefry_key01(uint32_t x0, uint32_t x1,
                                               uint32_t& o0, uint32_t& o1) {
    const uint32_t ks0 = 0u;
    const uint32_t ks1 = 1u;
    const uint32_t ks2 = 0x1BD11BDBu;  // 0x1BD11BDA ^ 0 ^ 1
    x0 += ks0; x1 += ks1;
#define TF_RND(r) { x0 += x1; x1 = rotl32(x1, r); x1 ^= x0; }
    TF_RND(13) TF_RND(15) TF_RND(26) TF_RND(6)
    x0 += ks1; x1 += ks2 + 1u;
    TF_RND(17) TF_RND(29) TF_RND(16) TF_RND(24)
    x0 += ks2; x1 += ks0 + 2u;
    TF_RND(13) TF_RND(15) TF_RND(26) TF_RND(6)
    x0 += ks0; x1 += ks1 + 3u;
    TF_RND(17) TF_RND(29) TF_RND(16) TF_RND(24)
    x0 += ks1; x1 += ks2 + 4u;
    TF_RND(13) TF_RND(15) TF_RND(26) TF_RND(6)
    x0 += ks2; x1 += ks0 + 5u;
#undef TF_RND
    o0 = x0; o1 = x1;
}

// jax_threefry_partitionable=True (default since jax 0.4.36):
// bits[i] = x0 ^ x1 of threefry2x32(key, (i >> 32, i & 0xffffffff)).
__device__ __forceinline__ int explore_index(int i, int ne) {
    uint32_t o0, o1;
    threefry_key01(0u, (uint32_t)i, o0, o1);
    uint32_t bits = o0 ^ o1;
    float u = __uint_as_float((bits >> 9) | 0x3F800000u) - 1.0f;
    int t = (int)floorf(u * (float)ne);
    return min(t, ne - 1);
}

// ---------- k1: phase-1 partial histograms (top0 x nb), LDS atomics only ----
__global__ void k_hist1(const int* __restrict__ top,
                        const int* __restrict__ nbid,
                        int* __restrict__ P, int n) {
    __shared__ int hist[HIST];
    for (int k = threadIdx.x; k < HIST; k += blockDim.x) hist[k] = 0;
    __syncthreads();
    int g = blockIdx.x, s = g >> 1, h = g & 1;
    int chunk = (n + NSLICE - 1) / NSLICE;
    int lo = s * chunk, hi = min(n, lo + chunk);
    for (int i = lo + threadIdx.x; i < hi; i += blockDim.x) {
        int nb = nbid[i];
        if ((nb >> 5) == h)
            atomicAdd(&hist[(nb & 31) * N_UNITS + top[i * 3]], 1);
    }
    __syncthreads();
    int* Pb = P + (size_t)g * HIST;
    for (int k = threadIdx.x; k < HIST; k += blockDim.x) Pb[k] = hist[k];
}

// ---------- k1b: fused reduce + sorted-table build (one block per nb) ------
// Replaces the 94.7us single-workgroup k_tables: 64 blocks x 512 threads,
// coalesced partial-sum + LDS prefix scan.
__global__ void k_reduce_tables(const int* __restrict__ P,
                                int* __restrict__ wtbl,
                                int* __restrict__ wne) {
    __shared__ int scan[512];
    int b = blockIdx.x;            // neighborhood id
    int u = threadIdx.x;           // unit id (512 threads, 400 active)
    int h = b >> 5;
    int local = (b & 31) * N_UNITS;
    int p = 0;
    if (u < N_UNITS) {
        int sum = 0;
        for (int s = 0; s < NSLICE; ++s)
            sum += P[(size_t)(s * 2 + h) * HIST + local + u];
        p = (sum > 0) ? 1 : 0;
    }
    scan[u] = p;
    __syncthreads();
    // Hillis-Steele inclusive scan over 512 entries
    for (int off = 1; off < 512; off <<= 1) {
        int add = (u >= off) ? scan[u - off] : 0;
        __syncthreads();
        scan[u] += add;
        __syncthreads();
    }
    if (p) wtbl[b * N_UNITS + scan[u] - 1] = u;
    if (u == 511) wne[b] = scan[511];
}

// ---------- k3: full-candidate partial histograms (all 10 columns) --------
__global__ void k_hist2(const int* __restrict__ top,
                        const int* __restrict__ usn,
                        const int* __restrict__ nbid,
                        const int* __restrict__ wtbl,
                        const int* __restrict__ wne,
                        int* __restrict__ P, int n) {
    __shared__ int hist[HIST];
    __shared__ int s_usn[N_UNITS * S];
    __shared__ int s_ne[N_NEIGHB];
    for (int k = threadIdx.x; k < HIST; k += blockDim.x) hist[k] = 0;
    for (int k = threadIdx.x; k < N_UNITS * S; k += blockDim.x) s_usn[k] = usn[k];
    for (int k = threadIdx.x; k < N_NEIGHB; k += blockDim.x) s_ne[k] = wne[k];
    __syncthreads();
    int g = blockIdx.x, s = g >> 1, h = g & 1;
    int chunk = (n + NSLICE - 1) / NSLICE;
    int lo = s * chunk, hi = min(n, lo + chunk);
    for (int i = lo + threadIdx.x; i < hi; i += blockDim.x) {
        int nb = nbid[i];
        if ((nb >> 5) != h) continue;
        int* hrow = &hist[(nb & 31) * N_UNITS];
        int t0 = top[i * 3], t1 = top[i * 3 + 1], t2 = top[i * 3 + 2];
        atomicAdd(&hrow[t0], 1);
        atomicAdd(&hrow[t1], 1);
        atomicAdd(&hrow[t2], 1);
        atomicAdd(&hrow[s_usn[t0 * 2]], 1); atomicAdd(&hrow[s_usn[t0 * 2 + 1]], 1);
        atomicAdd(&hrow[s_usn[t1 * 2]], 1); atomicAdd(&hrow[s_usn[t1 * 2 + 1]], 1);
        atomicAdd(&hrow[s_usn[t2 * 2]], 1); atomicAdd(&hrow[s_usn[t2 * 2 + 1]], 1);
        int ne = s_ne[nb];
        if (ne > 0) {
            int t = explore_index(i, ne);
            atomicAdd(&hrow[wtbl[nb * N_UNITS + t]], 1);
        }
    }
    __syncthreads();
    int* Pb = P + (size_t)g * HIST;
    for (int k = threadIdx.x; k < HIST; k += blockDim.x) Pb[k] = hist[k];
}

// ---------- k3b: reduce partials -> final counts (u-major, float) ----------
__global__ void k_reduce2(const int* __restrict__ P, float* __restrict__ out_counts) {
    int c = blockIdx.x * blockDim.x + threadIdx.x;
    if (c >= N_NEIGHB * N_UNITS) return;
    int nb = c / N_UNITS, u = c - nb * N_UNITS;
    int local = (nb & 31) * N_UNITS + u, h = nb >> 5;
    int sum = 0;
    for (int s = 0; s < NSLICE; ++s) sum += P[(size_t)(s * 2 + h) * HIST + local];
    out_counts[u * N_NEIGHB + nb] = (float)sum;
}

// ---------- k2: per-spike candidates + scores ----------
__global__ void k_main(const float* __restrict__ logliks,
                       const int* __restrict__ top,
                       const int* __restrict__ usn,
                       const int* __restrict__ nbid,
                       const int* __restrict__ wtbl,
                       const int* __restrict__ wne,
                       float* __restrict__ out_cand,
                       float* __restrict__ out_scores,
                       int n) {
    __shared__ int   s_usn[N_UNITS * S];
    __shared__ float s_ll[N_UNITS];
    __shared__ int   s_ne[N_NEIGHB];
    for (int k = threadIdx.x; k < N_UNITS * S; k += blockDim.x) s_usn[k] = usn[k];
    for (int k = threadIdx.x; k < N_UNITS; k += blockDim.x)     s_ll[k]  = logliks[k];
    for (int k = threadIdx.x; k < N_NEIGHB; k += blockDim.x)    s_ne[k]  = wne[k];
    __syncthreads();

    int i = blockIdx.x * blockDim.x + threadIdx.x;
    if (i >= n) return;

    int nb = nbid[i];
    int cand[T];
    cand[0] = top[i * 3 + 0];
    cand[1] = top[i * 3 + 1];
    cand[2] = top[i * 3 + 2];
#pragma unroll
    for (int c = 0; c < C; ++c) {
        cand[C + 2 * c]     = s_usn[cand[c] * 2 + 0];
        cand[C + 2 * c + 1] = s_usn[cand[c] * 2 + 1];
    }
    int ne = s_ne[nb];
    if (ne > 0) {
        int t = explore_index(i, ne);
        cand[T - 1] = wtbl[nb * N_UNITS + t];
    } else {
        cand[T - 1] = -1;
    }

    float vc[T], vs[T];
#pragma unroll
    for (int jj = 0; jj < T; ++jj) {
        bool dup = false;
#pragma unroll
        for (int k = 0; k < jj; ++k) dup |= (cand[k] == cand[jj]);
        int v = dup ? -1 : cand[jj];   // reference erases dups to -1
        vc[jj] = (float)v;
        vs[jj] = (v >= 0) ? s_ll[v] : 0.0f;
    }

    // 40*i bytes is 8B-aligned -> float2 vector stores (5 each vs 10 scalar)
    float2* oc2 = (float2*)(out_cand   + (size_t)i * T);
    float2* os2 = (float2*)(out_scores + (size_t)i * T);
#pragma unroll
    for (int jj = 0; jj < T / 2; ++jj) {
        oc2[jj] = make_float2(vc[2 * jj], vc[2 * jj + 1]);
        os2[jj] = make_float2(vs[2 * jj], vs[2 * jj + 1]);
    }
}

extern "C" void kernel_launch(void* const* d_in, const int* in_sizes, int n_in,
                              void* d_out, int out_size, void* d_ws, size_t ws_size,
                              hipStream_t stream) {
    const float* logliks = (const float*)d_in[0];
    const int*   top     = (const int*)d_in[1];
    const int*   usn     = (const int*)d_in[2];
    const int*   nbid    = (const int*)d_in[3];

    int n = in_sizes[3];          // N_SPIKES

    float* out        = (float*)d_out;
    float* out_cand   = out;
    float* out_counts = out + (size_t)n * T;
    float* out_scores = out_counts + (size_t)N_UNITS * N_NEIGHB;

    // Workspace: plain stores only.
    int* wtbl = (int*)d_ws;                 // 64*400 ints
    int* wne  = wtbl + N_NEIGHB * N_UNITS;  // 64 ints

    // Partial-histogram scratch lives in the scores region of d_out
    // (128 * 12800 ints = 6.55 MB << 40 MB); k_main overwrites it last.
    int* P = (int*)out_scores;

    const int bs = 256;
    k_hist1<<<2 * NSLICE, bs, 0, stream>>>(top, nbid, P, n);
    k_reduce_tables<<<N_NEIGHB, 512, 0, stream>>>(P, wtbl, wne);
    k_hist2<<<2 * NSLICE, bs, 0, stream>>>(top, usn, nbid, wtbl, wne, P, n);
    int m = N_NEIGHB * N_UNITS;
    k_reduce2<<<(m + bs - 1) / bs, bs, 0, stream>>>(P, out_counts);
    k_main<<<(n + bs - 1) / bs, bs, 0, stream>>>(logliks, top, usn, nbid, wtbl, wne,
                                                 out_cand, out_scores, n);
}

// Round 6
// 186.027 us; speedup vs baseline: 2.0153x; 1.3995x over previous
//
#include <hip/hip_runtime.h>
#include <stdint.h>

#define N_UNITS   400
#define N_NEIGHB  64
#define C         3
#define S         2
#define T         10      // C + C*S + E, E=1
#define NSLICE    128     // spike slices for histogram kernels
#define NQ        4       // neighborhood quarters
#define QNB       16      // neighborhoods per quarter
#define QH        (QNB * N_UNITS)   // 6400 ints = 25.6 KB LDS

// ---------- JAX Threefry-2x32, key = (0, 1) (jax.random.key(1)) ----------
__device__ __forceinline__ uint32_t rotl32(uint32_t x, int d) {
    return (x << d) | (x >> (32 - d));
}

__device__ __forceinline__ void threefry_key01(uint32_t x0, uint32_t x1,
                                               uint32_t& o0, uint32_t& o1) {
    const uint32_t ks0 = 0u;
    const uint32_t ks1 = 1u;
    const uint32_t ks2 = 0x1BD11BDBu;  // 0x1BD11BDA ^ 0 ^ 1
    x0 += ks0; x1 += ks1;
#define TF_RND(r) { x0 += x1; x1 = rotl32(x1, r); x1 ^= x0; }
    TF_RND(13) TF_RND(15) TF_RND(26) TF_RND(6)
    x0 += ks1; x1 += ks2 + 1u;
    TF_RND(17) TF_RND(29) TF_RND(16) TF_RND(24)
    x0 += ks2; x1 += ks0 + 2u;
    TF_RND(13) TF_RND(15) TF_RND(26) TF_RND(6)
    x0 += ks0; x1 += ks1 + 3u;
    TF_RND(17) TF_RND(29) TF_RND(16) TF_RND(24)
    x0 += ks1; x1 += ks2 + 4u;
    TF_RND(13) TF_RND(15) TF_RND(26) TF_RND(6)
    x0 += ks2; x1 += ks0 + 5u;
#undef TF_RND
    o0 = x0; o1 = x1;
}

// jax_threefry_partitionable=True (default since jax 0.4.36):
// bits[i] = x0 ^ x1 of threefry2x32(key, (i >> 32, i & 0xffffffff)).
__device__ __forceinline__ int explore_index(int i, int ne) {
    uint32_t o0, o1;
    threefry_key01(0u, (uint32_t)i, o0, o1);
    uint32_t bits = o0 ^ o1;
    float u = __uint_as_float((bits >> 9) | 0x3F800000u) - 1.0f;
    int t = (int)floorf(u * (float)ne);
    return min(t, ne - 1);
}

// ---------- kA: top-column partial histograms (H0 = top0, H12 = top1+top2) --
// grid = NSLICE*NQ blocks; block g: quarter q = g&3, slice s = g>>2.
// 3 LDS atomics per spike (was 10).
__global__ void k_histA(const int* __restrict__ top,
                        const int* __restrict__ nbid,
                        int* __restrict__ PA, int n, int chunk) {
    __shared__ int h0[QH];
    __shared__ int h12[QH];
    for (int k = threadIdx.x; k < QH; k += blockDim.x) { h0[k] = 0; h12[k] = 0; }
    __syncthreads();
    int q = blockIdx.x & 3, s = blockIdx.x >> 2;
    int lo = s * chunk, hi = min(n, lo + chunk);
    const int4* top4  = (const int4*)top;
    for (int i0 = lo + threadIdx.x * 4; i0 < hi; i0 += blockDim.x * 4) {
        if (i0 + 4 <= hi) {
            int4 nb4 = *(const int4*)(nbid + i0);
            int j = (i0 * 3) >> 2;
            int4 ta = top4[j], tb = top4[j + 1], tc = top4[j + 2];
#define PROC(nb, t0, t1, t2) if (((nb) >> 4) == q) { \
    int r = ((nb) & 15) * N_UNITS; \
    atomicAdd(&h0[r + (t0)], 1); atomicAdd(&h12[r + (t1)], 1); atomicAdd(&h12[r + (t2)], 1); }
            PROC(nb4.x, ta.x, ta.y, ta.z)
            PROC(nb4.y, ta.w, tb.x, tb.y)
            PROC(nb4.z, tb.z, tb.w, tc.x)
            PROC(nb4.w, tc.y, tc.z, tc.w)
        } else {
            for (int i = i0; i < hi; ++i)
                PROC(nbid[i], top[3 * i], top[3 * i + 1], top[3 * i + 2])
        }
#undef PROC
    }
    __syncthreads();
    int* Pb = PA + (size_t)blockIdx.x * 2 * QH;
    for (int k = threadIdx.x; k < QH; k += blockDim.x) {
        Pb[k] = h0[k];
        Pb[QH + k] = h12[k];
    }
}

// ---------- kB: reduce PA -> H0_full, H12_full (nb-major [64][400]) --------
__global__ void k_reduceA(const int* __restrict__ PA,
                          int* __restrict__ H0, int* __restrict__ H12) {
    int c = blockIdx.x * blockDim.x + threadIdx.x;   // 0 .. 2*25600
    if (c >= 2 * N_NEIGHB * N_UNITS) return;
    int a = c / (N_NEIGHB * N_UNITS);
    int cc = c - a * N_NEIGHB * N_UNITS;
    int nb = cc / N_UNITS, u = cc - nb * N_UNITS;
    int q = nb >> 4, r = nb & 15;
    int sum = 0;
    for (int s = 0; s < NSLICE; ++s)
        sum += PA[((size_t)(s * 4 + q) * 2 + a) * QH + r * N_UNITS + u];
    (a == 0 ? H0 : H12)[nb * N_UNITS + u] = sum;
}

// ---------- kC: per-neighborhood sorted unit tables from H0 ----------------
__global__ void k_tables(const int* __restrict__ H0,
                         int* __restrict__ wtbl, int* __restrict__ wne) {
    __shared__ int scan[512];
    int b = blockIdx.x, u = threadIdx.x;
    int p = (u < N_UNITS) ? (H0[b * N_UNITS + u] > 0 ? 1 : 0) : 0;
    scan[u] = p;
    __syncthreads();
    for (int off = 1; off < 512; off <<= 1) {
        int add = (u >= off) ? scan[u - off] : 0;
        __syncthreads();
        scan[u] += add;
        __syncthreads();
    }
    if (p) wtbl[b * N_UNITS + scan[u] - 1] = u;
    if (u == 511) wne[b] = scan[511];
}

// ---------- kD: explore-column partial histograms (1 atomic/spike) ---------
__global__ void k_histE(const int* __restrict__ nbid,
                        const int* __restrict__ wtbl,
                        const int* __restrict__ wne,
                        int* __restrict__ PD, int n, int chunk) {
    __shared__ int hist[QH];
    __shared__ int s_tbl[QH];
    __shared__ int s_ne[QNB];
    int q = blockIdx.x & 3, s = blockIdx.x >> 2;
    for (int k = threadIdx.x; k < QH; k += blockDim.x) {
        hist[k] = 0;
        s_tbl[k] = wtbl[q * QH + k];
    }
    for (int k = threadIdx.x; k < QNB; k += blockDim.x) s_ne[k] = wne[q * QNB + k];
    __syncthreads();
    int lo = s * chunk, hi = min(n, lo + chunk);
    for (int i0 = lo + threadIdx.x * 4; i0 < hi; i0 += blockDim.x * 4) {
#define PROCE(i, nb) if (((nb) >> 4) == q) { \
    int r = (nb) & 15; int ne = s_ne[r]; \
    if (ne > 0) { int t = explore_index((i), ne); \
        atomicAdd(&hist[r * N_UNITS + s_tbl[r * N_UNITS + t]], 1); } }
        if (i0 + 4 <= hi) {
            int4 nb4 = *(const int4*)(nbid + i0);
            PROCE(i0 + 0, nb4.x)
            PROCE(i0 + 1, nb4.y)
            PROCE(i0 + 2, nb4.z)
            PROCE(i0 + 3, nb4.w)
        } else {
            for (int i = i0; i < hi; ++i) PROCE(i, nbid[i])
        }
#undef PROCE
    }
    __syncthreads();
    int* Pb = PD + (size_t)blockIdx.x * QH;
    for (int k = threadIdx.x; k < QH; k += blockDim.x) Pb[k] = hist[k];
}

// ---------- kE: reduce PD -> HE (u-major [400][64], aliases out_counts) ----
__global__ void k_reducePD(const int* __restrict__ PD, int* __restrict__ HE) {
    int c = blockIdx.x * blockDim.x + threadIdx.x;   // 0 .. 25600
    if (c >= N_NEIGHB * N_UNITS) return;
    int nb = c / N_UNITS, u = c - nb * N_UNITS;
    int q = nb >> 4, r = nb & 15;
    int sum = 0;
    for (int s = 0; s < NSLICE; ++s)
        sum += PD[(size_t)(s * 4 + q) * QH + r * N_UNITS + u];
    HE[u * N_NEIGHB + nb] = sum;
}

// ---------- kF: finalize counts = H0 + H12 + search-expansion + HE ---------
// search contribution: counts[usn[u][s]][nb] += H3[u][nb], H3 = H0+H12.
// HE aliases out_counts (each thread reads then overwrites its own cell).
__global__ void k_finalize(const int* __restrict__ H0,
                           const int* __restrict__ H12,
                           const int* HE,              // aliases out_counts!
                           const int* __restrict__ usn,
                           float* out_counts) {
    __shared__ int s_c[N_UNITS];
    __shared__ int s_h3[N_UNITS];
    int b = blockIdx.x, u = threadIdx.x;
    if (u < N_UNITS) {
        int h3 = H0[b * N_UNITS + u] + H12[b * N_UNITS + u];
        s_h3[u] = h3;
        s_c[u] = h3;           // phase-1 (top0) + top1/top2 tail adds
    }
    __syncthreads();
    if (u < N_UNITS) {
        int h3 = s_h3[u];
        if (h3 > 0) {
            int2 nbr = ((const int2*)usn)[u];
            atomicAdd(&s_c[nbr.x], h3);
            atomicAdd(&s_c[nbr.y], h3);
        }
    }
    __syncthreads();
    if (u < N_UNITS) {
        int he = HE[u * N_NEIGHB + b];
        out_counts[u * N_NEIGHB + b] = (float)(s_c[u] + he);
    }
}

// ---------- k_main: per-spike candidates + scores (unchanged, verified) ----
__global__ void k_main(const float* __restrict__ logliks,
                       const int* __restrict__ top,
                       const int* __restrict__ usn,
                       const int* __restrict__ nbid,
                       const int* __restrict__ wtbl,
                       const int* __restrict__ wne,
                       float* __restrict__ out_cand,
                       float* __restrict__ out_scores,
                       int n) {
    __shared__ int   s_usn[N_UNITS * S];
    __shared__ float s_ll[N_UNITS];
    __shared__ int   s_ne[N_NEIGHB];
    for (int k = threadIdx.x; k < N_UNITS * S; k += blockDim.x) s_usn[k] = usn[k];
    for (int k = threadIdx.x; k < N_UNITS; k += blockDim.x)     s_ll[k]  = logliks[k];
    for (int k = threadIdx.x; k < N_NEIGHB; k += blockDim.x)    s_ne[k]  = wne[k];
    __syncthreads();

    int i = blockIdx.x * blockDim.x + threadIdx.x;
    if (i >= n) return;

    int nb = nbid[i];
    int cand[T];
    cand[0] = top[i * 3 + 0];
    cand[1] = top[i * 3 + 1];
    cand[2] = top[i * 3 + 2];
#pragma unroll
    for (int c = 0; c < C; ++c) {
        cand[C + 2 * c]     = s_usn[cand[c] * 2 + 0];
        cand[C + 2 * c + 1] = s_usn[cand[c] * 2 + 1];
    }
    int ne = s_ne[nb];
    if (ne > 0) {
        int t = explore_index(i, ne);
        cand[T - 1] = wtbl[nb * N_UNITS + t];
    } else {
        cand[T - 1] = -1;
    }

    float vc[T], vs[T];
#pragma unroll
    for (int jj = 0; jj < T; ++jj) {
        bool dup = false;
#pragma unroll
        for (int k = 0; k < jj; ++k) dup |= (cand[k] == cand[jj]);
        int v = dup ? -1 : cand[jj];   // reference erases dups to -1
        vc[jj] = (float)v;
        vs[jj] = (v >= 0) ? s_ll[v] : 0.0f;
    }

    float2* oc2 = (float2*)(out_cand   + (size_t)i * T);
    float2* os2 = (float2*)(out_scores + (size_t)i * T);
#pragma unroll
    for (int jj = 0; jj < T / 2; ++jj) {
        oc2[jj] = make_float2(vc[2 * jj], vc[2 * jj + 1]);
        os2[jj] = make_float2(vs[2 * jj], vs[2 * jj + 1]);
    }
}

extern "C" void kernel_launch(void* const* d_in, const int* in_sizes, int n_in,
                              void* d_out, int out_size, void* d_ws, size_t ws_size,
                              hipStream_t stream) {
    const float* logliks = (const float*)d_in[0];
    const int*   top     = (const int*)d_in[1];
    const int*   usn     = (const int*)d_in[2];
    const int*   nbid    = (const int*)d_in[3];

    int n = in_sizes[3];                              // N_SPIKES
    int chunk = ((n + NSLICE - 1) / NSLICE + 3) & ~3; // 4-aligned slice length

    float* out        = (float*)d_out;
    float* out_cand   = out;
    float* out_counts = out + (size_t)n * T;
    float* out_scores = out_counts + (size_t)N_UNITS * N_NEIGHB;

    // Scratch in the scores region (free until k_main, which runs last):
    //   PA: 512 blocks * 2*6400 ints = 26.2 MB   (offset 0)
    //   H0/H12: 25600 ints each                  (offset 6,553,600)
    //   PD: 512 * 6400 ints = 13.1 MB            (offset 0, reuses PA space)
    int* P   = (int*)out_scores;
    int* H0  = P + (size_t)NSLICE * NQ * 2 * QH;
    int* H12 = H0 + N_NEIGHB * N_UNITS;
    int* HE  = (int*)out_counts;   // 25600 ints, finalized in-place to float

    // Workspace (~103 KB): explore tables only.
    int* wtbl = (int*)d_ws;                 // [64][400]
    int* wne  = wtbl + N_NEIGHB * N_UNITS;  // [64]

    const int bs = 256;
    int m = N_NEIGHB * N_UNITS;
    k_histA   <<<NSLICE * NQ, bs, 0, stream>>>(top, nbid, P, n, chunk);
    k_reduceA <<<(2 * m + bs - 1) / bs, bs, 0, stream>>>(P, H0, H12);
    k_tables  <<<N_NEIGHB, 512, 0, stream>>>(H0, wtbl, wne);
    k_histE   <<<NSLICE * NQ, bs, 0, stream>>>(nbid, wtbl, wne, P, n, chunk);
    k_reducePD<<<(m + bs - 1) / bs, bs, 0, stream>>>(P, HE);
    k_finalize<<<N_NEIGHB, 512, 0, stream>>>(H0, H12, HE, usn, out_counts);
    k_main    <<<(n + bs - 1) / bs, bs, 0, stream>>>(logliks, top, usn, nbid,
                                                     wtbl, wne,
                                                     out_cand, out_scores, n);
}

// Round 7
// 183.603 us; speedup vs baseline: 2.0419x; 1.0132x over previous
//
#include <hip/hip_runtime.h>
#include <stdint.h>

#define N_UNITS   400
#define N_NEIGHB  64
#define C         3
#define S         2
#define T         10      // C + C*S + E, E=1
#define NSLICE    128     // spike slices for the histogram kernel
#define HALF_NB   32      // neighborhoods per half
#define HH        (HALF_NB * N_UNITS)   // 12800 packed ints = 51.2 KB LDS

// ---------- JAX Threefry-2x32, key = (0, 1) (jax.random.key(1)) ----------
__device__ __forceinline__ uint32_t rotl32(uint32_t x, int d) {
    return (x << d) | (x >> (32 - d));
}

__device__ __forceinline__ void threefry_key01(uint32_t x0, uint32_t x1,
                                               uint32_t& o0, uint32_t& o1) {
    const uint32_t ks0 = 0u;
    const uint32_t ks1 = 1u;
    const uint32_t ks2 = 0x1BD11BDBu;  // 0x1BD11BDA ^ 0 ^ 1
    x0 += ks0; x1 += ks1;
#define TF_RND(r) { x0 += x1; x1 = rotl32(x1, r); x1 ^= x0; }
    TF_RND(13) TF_RND(15) TF_RND(26) TF_RND(6)
    x0 += ks1; x1 += ks2 + 1u;
    TF_RND(17) TF_RND(29) TF_RND(16) TF_RND(24)
    x0 += ks2; x1 += ks0 + 2u;
    TF_RND(13) TF_RND(15) TF_RND(26) TF_RND(6)
    x0 += ks0; x1 += ks1 + 3u;
    TF_RND(17) TF_RND(29) TF_RND(16) TF_RND(24)
    x0 += ks1; x1 += ks2 + 4u;
    TF_RND(13) TF_RND(15) TF_RND(26) TF_RND(6)
    x0 += ks2; x1 += ks0 + 5u;
#undef TF_RND
    o0 = x0; o1 = x1;
}

// jax_threefry_partitionable=True (default since jax 0.4.36):
// bits[i] = x0 ^ x1 of threefry2x32(key, (i >> 32, i & 0xffffffff)).
__device__ __forceinline__ int explore_index(int i, int ne) {
    uint32_t o0, o1;
    threefry_key01(0u, (uint32_t)i, o0, o1);
    uint32_t bits = o0 ^ o1;
    float u = __uint_as_float((bits >> 9) | 0x3F800000u) - 1.0f;
    int t = (int)floorf(u * (float)ne);
    return min(t, ne - 1);
}

// ---------- kA: packed top-column partial histograms ----------------------
// One 32-bit word per (nb,u): lo16 = top0 count (H0), hi16 = top1+top2 (H12).
// Per-slice cell max 3*chunk < 2^16 -> no carry between halves.
// grid = NSLICE*2; block g: half h = g&1, slice s = g>>1. 3 LDS atomics/spike.
__global__ void k_histA(const int* __restrict__ top,
                        const int* __restrict__ nbid,
                        uint32_t* __restrict__ PA, int n, int chunk) {
    __shared__ uint32_t hist[HH];
    for (int k = threadIdx.x; k < HH; k += blockDim.x) hist[k] = 0u;
    __syncthreads();
    int h = blockIdx.x & 1, s = blockIdx.x >> 1;
    int lo = s * chunk, hi = min(n, lo + chunk);
    const int4* top4 = (const int4*)top;
#define PROC(nb, t0, t1, t2) if (((nb) >> 5) == h) { \
    int r = ((nb) & 31) * N_UNITS; \
    atomicAdd(&hist[r + (t0)], 1u); \
    atomicAdd(&hist[r + (t1)], 0x10000u); \
    atomicAdd(&hist[r + (t2)], 0x10000u); }
    for (int i0 = lo + threadIdx.x * 4; i0 < hi; i0 += blockDim.x * 4) {
        if (i0 + 4 <= hi) {
            int4 nb4 = *(const int4*)(nbid + i0);
            int j = (i0 * 3) >> 2;
            int4 ta = top4[j], tb = top4[j + 1], tc = top4[j + 2];
            PROC(nb4.x, ta.x, ta.y, ta.z)
            PROC(nb4.y, ta.w, tb.x, tb.y)
            PROC(nb4.z, tb.z, tb.w, tc.x)
            PROC(nb4.w, tc.y, tc.z, tc.w)
        } else {
            for (int i = i0; i < hi; ++i)
                PROC(nbid[i], top[3 * i], top[3 * i + 1], top[3 * i + 2])
        }
    }
#undef PROC
    __syncthreads();
    uint32_t* Pb = PA + (size_t)blockIdx.x * HH;
    for (int k = threadIdx.x; k < HH; k += blockDim.x) Pb[k] = hist[k];
}

// ---------- kB: fused reduce + tables + base counts -----------------------
// One block per neighborhood. Reduces PA -> (h0,h12); presence scan -> wtbl,
// wne; base counts = h3 + search-expansion (counts[usn[u][s]][b] += h3[u]);
// writes float base into out_counts. k_main's explore atomics finish it.
__global__ void k_tables_base(const uint32_t* __restrict__ PA,
                              const int* __restrict__ usn,
                              int* __restrict__ wtbl,
                              int* __restrict__ wne,
                              float* __restrict__ out_counts) {
    __shared__ int scan[512];
    __shared__ int s_c[N_UNITS];
    __shared__ int s_h3[N_UNITS];
    int b = blockIdx.x, u = threadIdx.x;
    int h = b >> 5;
    int base = (b & 31) * N_UNITS;
    int h0 = 0, h12 = 0;
    if (u < N_UNITS) {
        for (int s = 0; s < NSLICE; ++s) {
            uint32_t w = PA[(size_t)(s * 2 + h) * HH + base + u];
            h0  += (int)(w & 0xFFFFu);
            h12 += (int)(w >> 16);
        }
        int h3 = h0 + h12;
        s_h3[u] = h3;
        s_c[u] = h3;              // top0 + top1/top2 contributions
    }
    int p = (u < N_UNITS && h0 > 0) ? 1 : 0;
    scan[u] = p;
    __syncthreads();
    // Hillis-Steele inclusive scan over 512 entries
    for (int off = 1; off < 512; off <<= 1) {
        int add = (u >= off) ? scan[u - off] : 0;
        __syncthreads();
        scan[u] += add;
        __syncthreads();
    }
    if (p) wtbl[b * N_UNITS + scan[u] - 1] = u;
    if (u == 511) wne[b] = scan[511];
    // search-expansion: each top hit at (u,b) contributes its 2 neighbors
    if (u < N_UNITS) {
        int h3 = s_h3[u];
        if (h3 > 0) {
            int2 nbr = ((const int2*)usn)[u];
            atomicAdd(&s_c[nbr.x], h3);
            atomicAdd(&s_c[nbr.y], h3);
        }
    }
    __syncthreads();
    if (u < N_UNITS)
        out_counts[u * N_NEIGHB + b] = (float)s_c[u];
}

// ---------- k_main: candidates + scores + explore count atomics -----------
__global__ void k_main(const float* __restrict__ logliks,
                       const int* __restrict__ top,
                       const int* __restrict__ usn,
                       const int* __restrict__ nbid,
                       const int* __restrict__ wtbl,
                       const int* __restrict__ wne,
                       float* __restrict__ out_counts,
                       float* __restrict__ out_cand,
                       float* __restrict__ out_scores,
                       int n) {
    __shared__ int   s_usn[N_UNITS * S];
    __shared__ float s_ll[N_UNITS];
    __shared__ int   s_ne[N_NEIGHB];
    for (int k = threadIdx.x; k < N_UNITS * S; k += blockDim.x) s_usn[k] = usn[k];
    for (int k = threadIdx.x; k < N_UNITS; k += blockDim.x)     s_ll[k]  = logliks[k];
    for (int k = threadIdx.x; k < N_NEIGHB; k += blockDim.x)    s_ne[k]  = wne[k];
    __syncthreads();

    int i = blockIdx.x * blockDim.x + threadIdx.x;
    if (i >= n) return;

    int nb = nbid[i];
    int cand[T];
    cand[0] = top[i * 3 + 0];
    cand[1] = top[i * 3 + 1];
    cand[2] = top[i * 3 + 2];
#pragma unroll
    for (int c = 0; c < C; ++c) {
        cand[C + 2 * c]     = s_usn[cand[c] * 2 + 0];
        cand[C + 2 * c + 1] = s_usn[cand[c] * 2 + 1];
    }
    int ne = s_ne[nb];
    if (ne > 0) {
        int t = explore_index(i, ne);
        int ex = wtbl[nb * N_UNITS + t];
        cand[T - 1] = ex;
        // explore tail-add (pre-dup): finishes base counts from k_tables_base
        atomicAdd(&out_counts[ex * N_NEIGHB + nb], 1.0f);
    } else {
        cand[T - 1] = -1;
    }

    float vc[T], vs[T];
#pragma unroll
    for (int jj = 0; jj < T; ++jj) {
        bool dup = false;
#pragma unroll
        for (int k = 0; k < jj; ++k) dup |= (cand[k] == cand[jj]);
        int v = dup ? -1 : cand[jj];   // reference erases dups to -1
        vc[jj] = (float)v;
        vs[jj] = (v >= 0) ? s_ll[v] : 0.0f;
    }

    // 40*i bytes is 8B-aligned -> float2 vector stores
    float2* oc2 = (float2*)(out_cand   + (size_t)i * T);
    float2* os2 = (float2*)(out_scores + (size_t)i * T);
#pragma unroll
    for (int jj = 0; jj < T / 2; ++jj) {
        oc2[jj] = make_float2(vc[2 * jj], vc[2 * jj + 1]);
        os2[jj] = make_float2(vs[2 * jj], vs[2 * jj + 1]);
    }
}

extern "C" void kernel_launch(void* const* d_in, const int* in_sizes, int n_in,
                              void* d_out, int out_size, void* d_ws, size_t ws_size,
                              hipStream_t stream) {
    const float* logliks = (const float*)d_in[0];
    const int*   top     = (const int*)d_in[1];
    const int*   usn     = (const int*)d_in[2];
    const int*   nbid    = (const int*)d_in[3];

    int n = in_sizes[3];                              // N_SPIKES
    int chunk = ((n + NSLICE - 1) / NSLICE + 3) & ~3; // 4-aligned slice length

    float* out        = (float*)d_out;
    float* out_cand   = out;
    float* out_counts = out + (size_t)n * T;
    float* out_scores = out_counts + (size_t)N_UNITS * N_NEIGHB;

    // PA partials live in the scores region of d_out (256*12800*4 = 13.1 MB
    // << 40 MB); fully consumed by k_tables_base before k_main overwrites.
    uint32_t* PA = (uint32_t*)out_scores;

    // Workspace: explore tables only (~103 KB, plain stores).
    int* wtbl = (int*)d_ws;                 // [64][400]
    int* wne  = wtbl + N_NEIGHB * N_UNITS;  // [64]

    const int bs = 256;
    k_histA      <<<NSLICE * 2, bs, 0, stream>>>(top, nbid, PA, n, chunk);
    k_tables_base<<<N_NEIGHB, 512, 0, stream>>>(PA, usn, wtbl, wne, out_counts);
    k_main       <<<(n + bs - 1) / bs, bs, 0, stream>>>(logliks, top, usn, nbid,
                                                        wtbl, wne, out_counts,
                                                        out_cand, out_scores, n);
}